// Round 1
// baseline (588.191 us; speedup 1.0000x reference)
//
#include <hip/hip_runtime.h>

constexpr int BATCH = 4;
constexpr int SEQ   = 512;   // TQ == TS
constexpr int DM    = 512;
constexpr int NH    = 8;
constexpr int HD    = 64;
constexpr int NV    = 32000;
constexpr int NROWS = BATCH * SEQ;  // 2048

// ---------------- reductions ----------------
__device__ __forceinline__ float wave_reduce_max(float v) {
#pragma unroll
  for (int o = 32; o > 0; o >>= 1) v = fmaxf(v, __shfl_down(v, o, 64));
  return v;
}
__device__ __forceinline__ float wave_reduce_sum(float v) {
#pragma unroll
  for (int o = 32; o > 0; o >>= 1) v += __shfl_down(v, o, 64);
  return v;
}

// ---------------- GEMM: C[m,n] = sum_k A[m,k]*W[n,k] + bias[n] ----------------
// BM=64 BN=64 BK=16, 256 threads (16x16), 4x4 micro-tile. fp32 vector FMA.
__global__ __launch_bounds__(256)
void gemm_bias_kernel(const float* __restrict__ A, const float* __restrict__ W,
                      const float* __restrict__ bias, float* __restrict__ C,
                      int M, int N, int K) {
  __shared__ float As[16][68];  // [k][m], pad keeps float4 rows 16B-aligned (68*4=272)
  __shared__ float Ws[16][68];  // [k][n]
  const int tid = threadIdx.x;
  const int tx = tid & 15, ty = tid >> 4;
  const int m0 = blockIdx.y << 6, n0 = blockIdx.x << 6;
  const int r = tid >> 2;          // 0..63
  const int c = (tid & 3) << 2;    // 0,4,8,12
  float acc[4][4] = {};
  for (int k0 = 0; k0 < K; k0 += 16) {
    float4 av = *(const float4*)(A + (size_t)(m0 + r) * K + k0 + c);
    float4 wv = *(const float4*)(W + (size_t)(n0 + r) * K + k0 + c);
    As[c + 0][r] = av.x; As[c + 1][r] = av.y; As[c + 2][r] = av.z; As[c + 3][r] = av.w;
    Ws[c + 0][r] = wv.x; Ws[c + 1][r] = wv.y; Ws[c + 2][r] = wv.z; Ws[c + 3][r] = wv.w;
    __syncthreads();
#pragma unroll
    for (int kk = 0; kk < 16; ++kk) {
      float4 a4 = *(const float4*)(&As[kk][ty << 2]);
      float4 b4 = *(const float4*)(&Ws[kk][tx << 2]);
      float a[4] = {a4.x, a4.y, a4.z, a4.w};
      float b[4] = {b4.x, b4.y, b4.z, b4.w};
#pragma unroll
      for (int i = 0; i < 4; ++i)
#pragma unroll
        for (int j = 0; j < 4; ++j) acc[i][j] = fmaf(a[i], b[j], acc[i][j]);
    }
    __syncthreads();
  }
#pragma unroll
  for (int i = 0; i < 4; ++i) {
    const int m = m0 + (ty << 2) + i;
#pragma unroll
    for (int j = 0; j < 4; ++j) {
      const int n = n0 + (tx << 2) + j;
      C[(size_t)m * N + n] = acc[i][j] + bias[n];
    }
  }
}

// ---------------- scores[b,h,tq,ts] = 0.125 * Q_h . K_h ----------------
// grid (ts/64, tq/64, B*NH), block 256, K-dim = HD = 64 in one LDS tile.
__global__ __launch_bounds__(256)
void scores_kernel(const float* __restrict__ Qlin, const float* __restrict__ Klin,
                   float* __restrict__ scores) {
  const int bh = blockIdx.z, bb = bh >> 3, h = bh & 7;
  const int tq0 = blockIdx.y << 6, ts0 = blockIdx.x << 6;
  __shared__ float Qs[64 * 65];  // [tq][dh], stride 65 (2-way LDS conflict = free)
  __shared__ float Ks[64 * 65];  // [ts][dh]
  const int tid = threadIdx.x;
#pragma unroll
  for (int i = 0; i < 4; ++i) {
    const int idx = tid + (i << 8);
    const int rr = idx >> 4, cc = (idx & 15) << 2;
    float4 qv = *(const float4*)(Qlin + (size_t)(bb * SEQ + tq0 + rr) * DM + h * HD + cc);
    Qs[rr * 65 + cc + 0] = qv.x; Qs[rr * 65 + cc + 1] = qv.y;
    Qs[rr * 65 + cc + 2] = qv.z; Qs[rr * 65 + cc + 3] = qv.w;
    float4 kv = *(const float4*)(Klin + (size_t)(bb * SEQ + ts0 + rr) * DM + h * HD + cc);
    Ks[rr * 65 + cc + 0] = kv.x; Ks[rr * 65 + cc + 1] = kv.y;
    Ks[rr * 65 + cc + 2] = kv.z; Ks[rr * 65 + cc + 3] = kv.w;
  }
  __syncthreads();
  const int tx = tid & 15, ty = tid >> 4;
  float acc[4][4] = {};
#pragma unroll 4
  for (int k = 0; k < 64; ++k) {
    float a[4], b[4];
#pragma unroll
    for (int i = 0; i < 4; ++i) a[i] = Qs[(ty * 4 + i) * 65 + k];
#pragma unroll
    for (int j = 0; j < 4; ++j) b[j] = Ks[(tx * 4 + j) * 65 + k];
#pragma unroll
    for (int i = 0; i < 4; ++i)
#pragma unroll
      for (int j = 0; j < 4; ++j) acc[i][j] = fmaf(a[i], b[j], acc[i][j]);
  }
#pragma unroll
  for (int i = 0; i < 4; ++i) {
    const int tq = tq0 + ty * 4 + i;
#pragma unroll
    for (int j = 0; j < 4; ++j) {
      const int ts = ts0 + tx * 4 + j;
      scores[((size_t)bh * SEQ + tq) * SEQ + ts] = acc[i][j] * 0.125f;
    }
  }
}

// ---------------- per-(b,tq): softmax over ts for each head, mean over heads ----------------
__global__ __launch_bounds__(256)
void softmax_mean_kernel(const float* __restrict__ scores, float* __restrict__ attn) {
  __shared__ float redm[4], reds[4];
  const int row = blockIdx.x;          // b*SEQ + tq
  const int bb = row >> 9, tq = row & 511;
  const int tid = threadIdx.x;
  const int wid = tid >> 6, lane = tid & 63;
  float acc0 = 0.f, acc1 = 0.f;
  for (int h = 0; h < NH; ++h) {
    const float* srow = scores + ((size_t)(bb * NH + h) * SEQ + tq) * SEQ;
    const float s0 = srow[tid], s1 = srow[tid + 256];
    float m = wave_reduce_max(fmaxf(s0, s1));
    __syncthreads();
    if (lane == 0) redm[wid] = m;
    __syncthreads();
    m = fmaxf(fmaxf(redm[0], redm[1]), fmaxf(redm[2], redm[3]));
    const float e0 = __expf(s0 - m), e1 = __expf(s1 - m);
    float s = wave_reduce_sum(e0 + e1);
    __syncthreads();
    if (lane == 0) reds[wid] = s;
    __syncthreads();
    s = reds[0] + reds[1] + reds[2] + reds[3];
    const float inv = 1.f / s;
    acc0 = fmaf(e0, inv, acc0);
    acc1 = fmaf(e1, inv, acc1);
  }
  attn[(size_t)row * SEQ + tid]       = acc0 * 0.125f;
  attn[(size_t)row * SEQ + tid + 256] = acc1 * 0.125f;
}

// ---------------- dedup map: map[b][v] = first ts with src[b][ts]==v, else -1 ----------------
__global__ void build_map_kernel(const int* __restrict__ src, int* __restrict__ map) {
  const int bb = blockIdx.x, ts = threadIdx.x;
  const int v = src[bb * SEQ + ts];
  atomicCAS(&map[(size_t)bb * NV + v], -1, ts);  // winner's ts is the slot id
}

// ---------------- scatter attn weights into dense 512-slot arrays ----------------
__global__ void scatter_kernel(const float* __restrict__ attn, const int* __restrict__ src,
                               const int* __restrict__ map, float* __restrict__ aslots) {
  const int row = blockIdx.x, bb = row >> 9, ts = threadIdx.x;
  const int v = src[bb * SEQ + ts];
  const int rep = map[(size_t)bb * NV + v];
  atomicAdd(&aslots[(size_t)row * SEQ + rep], attn[(size_t)row * SEQ + ts]);
}

// ---------------- per-row: exp(slots) in place, denom, gate w ----------------
// denom = (NV - SEQ) + sum_slots exp(a_slot)   [absent vocab entries contribute exp(0)=1;
//  non-rep slots hold 0 -> exp=1, exactly standing in for the (SEQ - n_distinct) overcount]
__global__ __launch_bounds__(256)
void row_stats_kernel(float* __restrict__ aslots, const float* __restrict__ dec,
                      const float* __restrict__ Wfcw, const float* __restrict__ bfcw,
                      float* __restrict__ row_a, float* __restrict__ row_b) {
  __shared__ float red1[4], red2[4];
  const int row = blockIdx.x, tid = threadIdx.x;
  const int wid = tid >> 6, lane = tid & 63;
  const float a0 = aslots[(size_t)row * SEQ + tid];
  const float a1 = aslots[(size_t)row * SEQ + tid + 256];
  const float e0 = __expf(a0), e1 = __expf(a1);
  aslots[(size_t)row * SEQ + tid] = e0;
  aslots[(size_t)row * SEQ + tid + 256] = e1;
  const float es = wave_reduce_sum(e0 + e1);
  const float d = dec[(size_t)row * DM + tid] * Wfcw[tid] +
                  dec[(size_t)row * DM + tid + 256] * Wfcw[tid + 256];
  const float ds = wave_reduce_sum(d);
  if (lane == 0) { red1[wid] = es; red2[wid] = ds; }
  __syncthreads();
  if (tid == 0) {
    const float esum = red1[0] + red1[1] + red1[2] + red1[3];
    const float dsum = red2[0] + red2[1] + red2[2] + red2[3] + bfcw[0];
    const float w = 1.f / (1.f + __expf(-dsum));
    const float denom = (float)(NV - SEQ) + esum;
    row_a[row] = 1.f - w;
    row_b[row] = w / denom;
  }
}

// ---------------- out = (1-w)*p1 + (w/denom)*e, float4 streamed ----------------
__global__ __launch_bounds__(256)
void final_kernel(const float* __restrict__ p1, const int* __restrict__ map,
                  const float* __restrict__ expa, const float* __restrict__ row_a,
                  const float* __restrict__ row_b, float* __restrict__ out) {
  const size_t g = (size_t)blockIdx.x * 256 + threadIdx.x;  // one float4 per thread
  const int row = (int)(g / (NV / 4));
  const int q4  = (int)(g % (NV / 4));
  const int bb = row >> 9;
  const float4 p = ((const float4*)p1)[g];
  const int4 m = *(const int4*)(map + (size_t)bb * NV + (q4 << 2));
  const float ra = row_a[row], rb = row_b[row];
  const float* ea = expa + (size_t)row * SEQ;
  const float e0 = (m.x >= 0) ? ea[m.x] : 1.f;
  const float e1 = (m.y >= 0) ? ea[m.y] : 1.f;
  const float e2 = (m.z >= 0) ? ea[m.z] : 1.f;
  const float e3 = (m.w >= 0) ? ea[m.w] : 1.f;
  float4 o;
  o.x = fmaf(ra, p.x, rb * e0);
  o.y = fmaf(ra, p.y, rb * e1);
  o.z = fmaf(ra, p.z, rb * e2);
  o.w = fmaf(ra, p.w, rb * e3);
  ((float4*)out)[g] = o;
}

extern "C" void kernel_launch(void* const* d_in, const int* in_sizes, int n_in,
                              void* d_out, int out_size, void* d_ws, size_t ws_size,
                              hipStream_t stream) {
  const float* dec  = (const float*)d_in[1];
  const float* enc  = (const float*)d_in[2];
  const int*   src  = (const int*)d_in[3];
  const float* p1   = (const float*)d_in[4];
  const float* WfcQ = (const float*)d_in[5];
  const float* bfcQ = (const float*)d_in[6];
  const float* Wq   = (const float*)d_in[7];
  const float* bq   = (const float*)d_in[8];
  const float* Wk   = (const float*)d_in[9];
  const float* bk   = (const float*)d_in[10];
  const float* Wfcw = (const float*)d_in[11];
  const float* bfcw = (const float*)d_in[12];
  float* out = (float*)d_out;

  char* ws = (char*)d_ws;
  float* qlin   = (float*)(ws);                         //  4 MB
  float* klin   = (float*)(ws + (size_t)(4  << 20));    //  4 MB
  float* attn   = (float*)(ws + (size_t)(8  << 20));    //  4 MB
  float* aslots = (float*)(ws + (size_t)(12 << 20));    //  4 MB
  int*   map    = (int*)  (ws + (size_t)(16 << 20));    //  512 KB
  float* row_a  = (float*)(ws + (size_t)(17 << 20));    //  8 KB
  float* row_b  = (float*)(ws + (size_t)(17 << 20) + 16384);
  float* scores = (float*)(ws + (size_t)(18 << 20));    // 32 MB
  float* cq     = scores;  // cq is dead before scores is written

  hipMemsetAsync(map, 0xFF, (size_t)BATCH * NV * sizeof(int), stream);   // -1
  hipMemsetAsync(aslots, 0, (size_t)NROWS * SEQ * sizeof(float), stream);

  build_map_kernel<<<BATCH, SEQ, 0, stream>>>(src, map);

  dim3 gg(DM / 64, NROWS / 64);
  gemm_bias_kernel<<<gg, 256, 0, stream>>>(dec, WfcQ, bfcQ, cq,   NROWS, DM, DM);
  gemm_bias_kernel<<<gg, 256, 0, stream>>>(cq,  Wq,   bq,   qlin, NROWS, DM, DM);
  gemm_bias_kernel<<<gg, 256, 0, stream>>>(enc, Wk,   bk,   klin, NROWS, DM, DM);

  dim3 sg(SEQ / 64, SEQ / 64, BATCH * NH);
  scores_kernel<<<sg, 256, 0, stream>>>(qlin, klin, scores);

  softmax_mean_kernel<<<NROWS, 256, 0, stream>>>(scores, attn);
  scatter_kernel<<<NROWS, SEQ, 0, stream>>>(attn, src, map, aslots);
  row_stats_kernel<<<NROWS, 256, 0, stream>>>(aslots, dec, Wfcw, bfcw, row_a, row_b);

  final_kernel<<<(NROWS * (NV / 4)) / 256, 256, 0, stream>>>(p1, map, aslots, row_a, row_b, out);
}

// Round 2
// 518.877 us; speedup vs baseline: 1.1336x; 1.1336x over previous
//
#include <hip/hip_runtime.h>

constexpr int BATCH = 4;
constexpr int SEQ   = 512;   // TQ == TS
constexpr int DM    = 512;
constexpr int NH    = 8;
constexpr int NV    = 32000;
constexpr int NROWS = BATCH * SEQ;  // 2048

typedef short short8 __attribute__((ext_vector_type(8)));
typedef float floatx4 __attribute__((ext_vector_type(4)));

// ---------------- helpers ----------------
__device__ __forceinline__ float wave_reduce_max(float v) {
#pragma unroll
  for (int o = 32; o > 0; o >>= 1) v = fmaxf(v, __shfl_down(v, o, 64));
  return v;
}
__device__ __forceinline__ float wave_reduce_sum(float v) {
#pragma unroll
  for (int o = 32; o > 0; o >>= 1) v += __shfl_down(v, o, 64);
  return v;
}
__device__ __forceinline__ unsigned short f2bf(float f) {
  unsigned u = __float_as_uint(f);
  u += 0x7FFFu + ((u >> 16) & 1u);   // RNE
  return (unsigned short)(u >> 16);
}
__device__ __forceinline__ float bf2f(unsigned short b) {
  return __uint_as_float(((unsigned)b) << 16);
}

// ---------------- fp32 -> bf16 convert ----------------
__global__ __launch_bounds__(256)
void convert_bf16_kernel(const float* __restrict__ in, unsigned short* __restrict__ out, int n4) {
  const int i = blockIdx.x * 256 + threadIdx.x;
  if (i < n4) {
    const float4 v = ((const float4*)in)[i];
    ushort4 o;
    o.x = f2bf(v.x); o.y = f2bf(v.y); o.z = f2bf(v.z); o.w = f2bf(v.w);
    ((ushort4*)out)[i] = o;
  }
}

// ---------------- weight fold: Wqc[m,n] = sum_k Wq[m,k]*WfcQ[k,n], bf16 out ----------------
__global__ __launch_bounds__(256)
void wfold_kernel(const float* __restrict__ Wq, const float* __restrict__ WfcQ,
                  unsigned short* __restrict__ Wqc) {
  __shared__ float As[16][68];
  __shared__ float Bs[16][68];
  const int tid = threadIdx.x, tx = tid & 15, ty = tid >> 4;
  const int m0 = blockIdx.y << 6, n0 = blockIdx.x << 6;
  const int r = tid >> 2, c = (tid & 3) << 2;
  float acc[4][4] = {};
  for (int k0 = 0; k0 < DM; k0 += 16) {
    const float4 av = *(const float4*)(Wq + (size_t)(m0 + r) * DM + k0 + c);
    As[c + 0][r] = av.x; As[c + 1][r] = av.y; As[c + 2][r] = av.z; As[c + 3][r] = av.w;
    const float4 bv = *(const float4*)(WfcQ + (size_t)(k0 + ty) * DM + n0 + (tx << 2));
    *(float4*)(&Bs[ty][tx << 2]) = bv;
    __syncthreads();
#pragma unroll
    for (int kk = 0; kk < 16; ++kk) {
      const float4 a4 = *(const float4*)(&As[kk][ty << 2]);
      const float4 b4 = *(const float4*)(&Bs[kk][tx << 2]);
      const float a[4] = {a4.x, a4.y, a4.z, a4.w};
      const float b[4] = {b4.x, b4.y, b4.z, b4.w};
#pragma unroll
      for (int i = 0; i < 4; ++i)
#pragma unroll
        for (int j = 0; j < 4; ++j) acc[i][j] = fmaf(a[i], b[j], acc[i][j]);
    }
    __syncthreads();
  }
#pragma unroll
  for (int i = 0; i < 4; ++i)
#pragma unroll
    for (int j = 0; j < 4; ++j)
      Wqc[(size_t)(m0 + (ty << 2) + i) * DM + n0 + (tx << 2) + j] = f2bf(acc[i][j]);
}

// ---------------- bq2[n] = bq[n] + dot(Wq[n,:], bfcQ) ----------------
__global__ __launch_bounds__(512)
void bias_fold_kernel(const float* __restrict__ Wq, const float* __restrict__ bfcQ,
                      const float* __restrict__ bq, float* __restrict__ bq2) {
  const int tid = threadIdx.x, h = tid >> 6, l = tid & 63;
  const int n = blockIdx.x * 8 + h;
  float s = 0.f;
#pragma unroll
  for (int t = 0; t < 8; ++t) {
    const int j = l + 64 * t;
    s = fmaf(Wq[(size_t)n * DM + j], bfcQ[j], s);
  }
  s = wave_reduce_sum(s);
  if (l == 0) bq2[n] = bq[n] + s;
}

// ---------------- bf16 MFMA GEMM: C[m,n] = A[m,:] . W[n,:] + bias[n], bf16 out ----------------
// 64x64 tile, 256 threads (4 waves), BK=64 (2 mfma k-steps), z selects {qlin, klin} problem.
__global__ __launch_bounds__(256)
void gemm_mfma_kernel(const unsigned short* __restrict__ A0, const unsigned short* __restrict__ W0,
                      const float* __restrict__ b0, unsigned short* __restrict__ C0,
                      const unsigned short* __restrict__ A1, const unsigned short* __restrict__ W1,
                      const float* __restrict__ b1, unsigned short* __restrict__ C1) {
  const unsigned short* A; const unsigned short* W; const float* bias; unsigned short* C;
  if (blockIdx.z == 0) { A = A0; W = W0; bias = b0; C = C0; }
  else                 { A = A1; W = W1; bias = b1; C = C1; }
  const int m0 = blockIdx.y << 6, n0 = blockIdx.x << 6;
  __shared__ __align__(16) unsigned short As[64 * 72];  // row stride 72 bf16 = 144 B (16B-aligned, bank-spread)
  __shared__ __align__(16) unsigned short Ws[64 * 72];
  const int tid = threadIdx.x;
  const int wv = tid >> 6, l = tid & 63;
  const int lm = l & 15, lq = l >> 4;
  floatx4 acc[4] = {};
  for (int k0 = 0; k0 < DM; k0 += 64) {
#pragma unroll
    for (int i = 0; i < 2; ++i) {
      const int ch = tid + (i << 8);
      const int row = ch >> 3, c8 = (ch & 7) << 3;
      *(int4*)(&As[row * 72 + c8]) = *(const int4*)(A + (size_t)(m0 + row) * DM + k0 + c8);
      *(int4*)(&Ws[row * 72 + c8]) = *(const int4*)(W + (size_t)(n0 + row) * DM + k0 + c8);
    }
    __syncthreads();
#pragma unroll
    for (int ks = 0; ks < 64; ks += 32) {
      const short8 a = *(const short8*)(&As[(16 * wv + lm) * 72 + ks + lq * 8]);
#pragma unroll
      for (int c = 0; c < 4; ++c) {
        const short8 b = *(const short8*)(&Ws[(16 * c + lm) * 72 + ks + lq * 8]);
        acc[c] = __builtin_amdgcn_mfma_f32_16x16x32_bf16(a, b, acc[c], 0, 0, 0);
      }
    }
    __syncthreads();
  }
#pragma unroll
  for (int c = 0; c < 4; ++c) {
    const int col = n0 + 16 * c + lm;
    const float bv = bias[col];
#pragma unroll
    for (int r = 0; r < 4; ++r) {
      const int row = m0 + 16 * wv + lq * 4 + r;
      C[(size_t)row * DM + col] = f2bf(acc[c][r] + bv);
    }
  }
}

// ---------------- scores[b,h,tq,ts] = 0.125 * Q_h . K_h  (bf16 MFMA, bf16 out) ----------------
__global__ __launch_bounds__(256)
void scores_mfma_kernel(const unsigned short* __restrict__ Q, const unsigned short* __restrict__ Kk,
                        unsigned short* __restrict__ scores) {
  const int bh = blockIdx.z, bb = bh >> 3, h = bh & 7;
  const int tq0 = blockIdx.y << 6, ts0 = blockIdx.x << 6;
  __shared__ __align__(16) unsigned short Qs[64 * 72];
  __shared__ __align__(16) unsigned short Ks[64 * 72];
  const int tid = threadIdx.x;
  const int wv = tid >> 6, l = tid & 63;
  const int lm = l & 15, lq = l >> 4;
#pragma unroll
  for (int i = 0; i < 2; ++i) {
    const int ch = tid + (i << 8);
    const int row = ch >> 3, c8 = (ch & 7) << 3;
    *(int4*)(&Qs[row * 72 + c8]) =
        *(const int4*)(Q + (size_t)(bb * SEQ + tq0 + row) * DM + h * 64 + c8);
    *(int4*)(&Ks[row * 72 + c8]) =
        *(const int4*)(Kk + (size_t)(bb * SEQ + ts0 + row) * DM + h * 64 + c8);
  }
  __syncthreads();
  floatx4 acc[4] = {};
#pragma unroll
  for (int ks = 0; ks < 64; ks += 32) {
    const short8 a = *(const short8*)(&Qs[(16 * wv + lm) * 72 + ks + lq * 8]);
#pragma unroll
    for (int c = 0; c < 4; ++c) {
      const short8 b = *(const short8*)(&Ks[(16 * c + lm) * 72 + ks + lq * 8]);
      acc[c] = __builtin_amdgcn_mfma_f32_16x16x32_bf16(a, b, acc[c], 0, 0, 0);
    }
  }
#pragma unroll
  for (int c = 0; c < 4; ++c) {
    const int ts = ts0 + 16 * c + lm;
#pragma unroll
    for (int r = 0; r < 4; ++r) {
      const int tq = tq0 + 16 * wv + lq * 4 + r;
      scores[((size_t)bh * SEQ + tq) * SEQ + ts] = f2bf(acc[c][r] * 0.125f);
    }
  }
}

// ---------------- dedup map: map[b][v] = first ts with src[b][ts]==v, else -1 ----------------
__global__ void build_map_kernel(const int* __restrict__ src, int* __restrict__ map) {
  const int bb = blockIdx.x, ts = threadIdx.x;
  const int v = src[bb * SEQ + ts];
  atomicCAS(&map[(size_t)bb * NV + v], -1, ts);
}

// ---------------- fused: per-(b,tq) softmax(8 heads) + mean + scatter + exp + denom + gate ----
// block = 512 threads (8 waves, one per head)
__global__ __launch_bounds__(512)
void softmax_fused_kernel(const unsigned short* __restrict__ scores, const int* __restrict__ src,
                          const int* __restrict__ map, const float* __restrict__ dec,
                          const float* __restrict__ Wfcw, const float* __restrict__ bfcw,
                          float* __restrict__ expa, float* __restrict__ row_a,
                          float* __restrict__ row_b) {
  __shared__ float hp[8 * 520];
  __shared__ float aslot[512];
  __shared__ float r1[8], r2[8];
  const int row = blockIdx.x, bb = row >> 9, tq = row & 511;
  const int tid = threadIdx.x, h = tid >> 6, l = tid & 63;
  aslot[tid] = 0.f;
  // wave h: softmax over ts for head h; lane l owns ts = 8l..8l+7
  const unsigned short* srow = scores + ((size_t)(bb * NH + h) * SEQ + tq) * SEQ;
  union { int4 v; unsigned short u[8]; } U;
  U.v = *(const int4*)(srow + 8 * l);
  float s[8];
#pragma unroll
  for (int i = 0; i < 8; ++i) s[i] = bf2f(U.u[i]);
  float m = s[0];
#pragma unroll
  for (int i = 1; i < 8; ++i) m = fmaxf(m, s[i]);
  m = wave_reduce_max(m);
  m = __shfl(m, 0, 64);
  float e[8], sum = 0.f;
#pragma unroll
  for (int i = 0; i < 8; ++i) { e[i] = __expf(s[i] - m); sum += e[i]; }
  sum = wave_reduce_sum(sum);
  sum = __shfl(sum, 0, 64);
  const float inv = 1.f / sum;
  float4 p0, p1v;
  p0.x = e[0] * inv; p0.y = e[1] * inv; p0.z = e[2] * inv; p0.w = e[3] * inv;
  p1v.x = e[4] * inv; p1v.y = e[5] * inv; p1v.z = e[6] * inv; p1v.w = e[7] * inv;
  *(float4*)(&hp[h * 520 + 8 * l])     = p0;
  *(float4*)(&hp[h * 520 + 8 * l + 4]) = p1v;
  __syncthreads();
  // thread t owns ts = t: head-mean, scatter to dedup slot in LDS
  float a = 0.f;
#pragma unroll
  for (int h2 = 0; h2 < 8; ++h2) a += hp[h2 * 520 + tid];
  a *= 0.125f;
  const int sv = src[bb * SEQ + tid];
  const int rep = map[(size_t)bb * NV + sv];
  atomicAdd(&aslot[rep], a);
  __syncthreads();
  // exp, write expa row, reduce denom and gate dot
  const float ev = __expf(aslot[tid]);
  expa[(size_t)row * SEQ + tid] = ev;
  const float d = dec[(size_t)row * DM + tid] * Wfcw[tid];
  float es = wave_reduce_sum(ev);
  float ds = wave_reduce_sum(d);
  if (l == 0) { r1[h] = es; r2[h] = ds; }
  __syncthreads();
  if (tid == 0) {
    float esum = 0.f, dsum = bfcw[0];
#pragma unroll
    for (int i = 0; i < 8; ++i) { esum += r1[i]; dsum += r2[i]; }
    const float w = 1.f / (1.f + __expf(-dsum));
    row_a[row] = 1.f - w;
    row_b[row] = w / ((float)(NV - SEQ) + esum);
  }
}

// ---------------- out = (1-w)*p1 + (w/denom)*e, float4 streamed ----------------
__global__ __launch_bounds__(256)
void final_kernel(const float* __restrict__ p1, const int* __restrict__ map,
                  const float* __restrict__ expa, const float* __restrict__ row_a,
                  const float* __restrict__ row_b, float* __restrict__ out) {
  const size_t g = (size_t)blockIdx.x * 256 + threadIdx.x;  // one float4 per thread
  const int row = (int)(g / (NV / 4));
  const int q4  = (int)(g % (NV / 4));
  const int bb = row >> 9;
  const float4 p = ((const float4*)p1)[g];
  const int4 m = *(const int4*)(map + (size_t)bb * NV + (q4 << 2));
  const float ra = row_a[row], rb = row_b[row];
  const float* ea = expa + (size_t)row * SEQ;
  const float e0 = (m.x >= 0) ? ea[m.x] : 1.f;
  const float e1 = (m.y >= 0) ? ea[m.y] : 1.f;
  const float e2 = (m.z >= 0) ? ea[m.z] : 1.f;
  const float e3 = (m.w >= 0) ? ea[m.w] : 1.f;
  float4 o;
  o.x = fmaf(ra, p.x, rb * e0);
  o.y = fmaf(ra, p.y, rb * e1);
  o.z = fmaf(ra, p.z, rb * e2);
  o.w = fmaf(ra, p.w, rb * e3);
  ((float4*)out)[g] = o;
}

extern "C" void kernel_launch(void* const* d_in, const int* in_sizes, int n_in,
                              void* d_out, int out_size, void* d_ws, size_t ws_size,
                              hipStream_t stream) {
  const float* dec  = (const float*)d_in[1];
  const float* enc  = (const float*)d_in[2];
  const int*   src  = (const int*)d_in[3];
  const float* p1   = (const float*)d_in[4];
  const float* WfcQ = (const float*)d_in[5];
  const float* bfcQ = (const float*)d_in[6];
  const float* Wq   = (const float*)d_in[7];
  const float* bq   = (const float*)d_in[8];
  const float* Wk   = (const float*)d_in[9];
  const float* bk   = (const float*)d_in[10];
  const float* Wfcw = (const float*)d_in[11];
  const float* bfcw = (const float*)d_in[12];
  float* out = (float*)d_out;

  char* ws = (char*)d_ws;
  int*            map     = (int*)(ws);                                   // 512 KB
  unsigned short* dec_bf  = (unsigned short*)(ws + (size_t)( 1 << 20));   // 2 MB
  unsigned short* enc_bf  = (unsigned short*)(ws + (size_t)( 3 << 20));   // 2 MB
  unsigned short* wk_bf   = (unsigned short*)(ws + (size_t)( 5 << 20));   // 512 KB
  unsigned short* wqc_bf  = (unsigned short*)(ws + (size_t)( 5 << 20) + (512 << 10));
  float*          bq2     = (float*)(ws + (size_t)( 6 << 20));            // 2 KB
  float*          row_a   = (float*)(ws + (size_t)( 6 << 20) + (64 << 10));
  float*          row_b   = (float*)(ws + (size_t)( 6 << 20) + (128 << 10));
  unsigned short* qlin_bf = (unsigned short*)(ws + (size_t)( 7 << 20));   // 2 MB
  unsigned short* klin_bf = (unsigned short*)(ws + (size_t)( 9 << 20));   // 2 MB
  float*          expa    = (float*)(ws + (size_t)(11 << 20));            // 4 MB
  unsigned short* scores  = (unsigned short*)(ws + (size_t)(16 << 20));   // 16.8 MB

  hipMemsetAsync(map, 0xFF, (size_t)BATCH * NV * sizeof(int), stream);
  build_map_kernel<<<BATCH, SEQ, 0, stream>>>(src, map);

  convert_bf16_kernel<<<1024, 256, 0, stream>>>(dec, dec_bf, NROWS * DM / 4);
  convert_bf16_kernel<<<1024, 256, 0, stream>>>(enc, enc_bf, NROWS * DM / 4);
  convert_bf16_kernel<<<256, 256, 0, stream>>>(Wk, wk_bf, DM * DM / 4);

  wfold_kernel<<<dim3(8, 8), 256, 0, stream>>>(Wq, WfcQ, wqc_bf);
  bias_fold_kernel<<<64, 512, 0, stream>>>(Wq, bfcQ, bq, bq2);

  gemm_mfma_kernel<<<dim3(8, 32, 2), 256, 0, stream>>>(
      dec_bf, wqc_bf, bq2, qlin_bf, enc_bf, wk_bf, bk, klin_bf);

  scores_mfma_kernel<<<dim3(8, 8, 32), 256, 0, stream>>>(qlin_bf, klin_bf, scores);

  softmax_fused_kernel<<<NROWS, 512, 0, stream>>>(scores, src, map, dec, Wfcw, bfcw,
                                                  expa, row_a, row_b);

  final_kernel<<<(NROWS * (NV / 4)) / 256, 256, 0, stream>>>(p1, map, expa, row_a, row_b, out);
}